// Round 16
// baseline (478.158 us; speedup 1.0000x reference)
//
#include <hip/hip_runtime.h>

#define EPSV 1e-5f
#define BSH 8           // bucket shift: 256 nodes per bucket
#define BSZ 256
#define SBR 416         // statsred blocks

// bf16x2 helpers (bf16 = top 16 bits of fp32; element 2f = low half)
__device__ inline float blo(unsigned u) { return __uint_as_float(u << 16); }
__device__ inline float bhi(unsigned u) { return __uint_as_float(u & 0xFFFF0000u); }
__device__ inline unsigned rne16(float v) {
    unsigned u = __float_as_uint(v);
    return (u + 0x7FFFu + ((u >> 16) & 1u)) >> 16;
}
__device__ inline unsigned pk(float lo, float hi) {
    return (rne16(hi) << 16) | rne16(lo);
}

// ====== CSR build: deterministic multisplit (histmat, no global atomics) ===

// per-block LDS hist -> coalesced 4KB row store to histmat[block][1024].
// Block 0 also zeroes k_scanb's ticket (replaces the memset dispatch).
__global__ __launch_bounds__(256) void k_hist(const int* __restrict__ dst,
                                              int* __restrict__ histmat,
                                              int* __restrict__ tick3, int E) {
    __shared__ int hist[1024];
    int t = threadIdx.x;
    if (blockIdx.x == 0 && t == 0) tick3[0] = 0;
#pragma unroll
    for (int i = 0; i < 4; i++) hist[t + 256 * i] = 0;
    __syncthreads();
    int e0 = blockIdx.x * 4096;
#pragma unroll
    for (int r = 0; r < 16; r++) {
        int e = e0 + r * 256 + t;
        if (e < E) atomicAdd(&hist[dst[e] >> BSH], 1);
    }
    __syncthreads();
    int* hrow = histmat + (size_t)blockIdx.x * 1024;
#pragma unroll
    for (int i = 0; i < 4; i++) hrow[t + 256 * i] = hist[t + 256 * i];
}

// one wave per bucket: exclusive scan of histmat column (over blocks),
// in-place; bucket total -> bcount. Last block (ticket) scans bcount->bstart
// and zeroes the statsred partials/tickets for this launch.
__global__ __launch_bounds__(256) void k_scanb(int* __restrict__ histmat,
                                               int* __restrict__ bcount,
                                               int* __restrict__ bstart,
                                               int* __restrict__ ticket,
                                               float* __restrict__ ps3,
                                               int* __restrict__ tick012,
                                               int NBLK) {
    int t = threadIdx.x;
    int wv = t >> 6, lane = t & 63;
    int bucket = blockIdx.x * 4 + wv;     // grid 256 -> 1024 buckets
    int run = 0;
    int lim = (NBLK + 63) & ~63;
    for (int i = lane; i < lim; i += 64) {
        int v = (i < NBLK) ? histmat[(size_t)i * 1024 + bucket] : 0;
        int s = v;
#pragma unroll
        for (int d = 1; d < 64; d <<= 1) {
            int up = __shfl_up(s, d, 64);
            if (lane >= d) s += up;
        }
        if (i < NBLK) histmat[(size_t)i * 1024 + bucket] = run + s - v;
        run += __shfl(s, 63, 64);
    }
    if (lane == 0) bcount[bucket] = run;
    __syncthreads();
    __shared__ int lastflag;
    if (t == 0) {
        __threadfence();
        lastflag = (atomicAdd(ticket, 1) == (int)gridDim.x - 1);
    }
    __syncthreads();
    if (lastflag) {
        for (int i = t; i < 384; i += 256) ps3[i] = 0.0f;
        if (t < 3) tick012[t] = 0;
        int base = t * 4;
        int c[4], s2 = 0;
#pragma unroll
        for (int i = 0; i < 4; i++) {
            c[i] = atomicAdd(&bcount[base + i], 0);   // device-coherent read
            s2 += c[i];
        }
        __shared__ int ls[256];
        ls[t] = s2;
        __syncthreads();
        for (int off = 1; off < 256; off <<= 1) {
            int x = (t >= off) ? ls[t - off] : 0;
            __syncthreads();
            ls[t] += x;
            __syncthreads();
        }
        int run2 = (t == 0) ? 0 : ls[t - 1];
#pragma unroll
        for (int i = 0; i < 4; i++) {
            bstart[base + i] = run2;
            run2 += c[i];
        }
        if (t == 255) bstart[1024] = ls[255];
    }
}

// single-pass split: offsets precomputed (bstart + histmat excl), rank via
// LDS atomic. pack: (dst_local << 22) | src   (src < 2^22, dst_local < 256)
__global__ __launch_bounds__(256) void k_split(const int* __restrict__ src,
                                               const int* __restrict__ dst,
                                               const int* __restrict__ histmat,
                                               const int* __restrict__ bstart,
                                               unsigned* __restrict__ pairs, int E) {
    __shared__ int hist[1024];
    __shared__ int gb[1024];
    int t = threadIdx.x;
    int e0 = blockIdx.x * 4096;
    const int* hrow = histmat + (size_t)blockIdx.x * 1024;
    int sreg[16], dreg[16];
#pragma unroll
    for (int i = 0; i < 4; i++) {
        int bk = t + 256 * i;
        hist[bk] = 0;
        gb[bk] = bstart[bk] + hrow[bk];
    }
#pragma unroll
    for (int r = 0; r < 16; r++) {
        int e = e0 + r * 256 + t;
        if (e < E) {
            sreg[r] = src[e];
            dreg[r] = dst[e];
        } else {
            dreg[r] = -1;
        }
    }
    __syncthreads();
#pragma unroll
    for (int r = 0; r < 16; r++) {
        if (dreg[r] >= 0) {
            int bk = dreg[r] >> BSH;
            int rk = atomicAdd(&hist[bk], 1);
            pairs[gb[bk] + rk] = ((unsigned)(dreg[r] & (BSZ - 1)) << 22) |
                                 (unsigned)sreg[r];
        }
    }
}

// one block per 256-node bucket
__global__ __launch_bounds__(256) void k_build(const unsigned* __restrict__ pairs,
                                               const int* __restrict__ bstart,
                                               int* __restrict__ rowptr,
                                               int* __restrict__ rowend,
                                               float* __restrict__ dinv,
                                               int* __restrict__ colidx, int N) {
    int bid = blockIdx.x, t = threadIdx.x;
    int n0 = bid << BSH;
    int e0 = bstart[bid], e1 = bstart[bid + 1];
    __shared__ int cnt[256];
    __shared__ int ls[256];
    __shared__ int cur[256];
    cnt[t] = 0;
    __syncthreads();
    for (int e = e0 + t; e < e1; e += 256)
        atomicAdd(&cnt[pairs[e] >> 22], 1);
    __syncthreads();
    ls[t] = cnt[t];
    __syncthreads();
    for (int off = 1; off < 256; off <<= 1) {
        int x = (t >= off) ? ls[t - off] : 0;
        __syncthreads();
        ls[t] += x;
        __syncthreads();
    }
    int start = e0 + ((t == 0) ? 0 : ls[t - 1]);
    cur[t] = start;
    int node = n0 + t;
    if (node < N) {
        rowptr[node] = start;
        rowend[node] = start + cnt[t];
        dinv[node] = rsqrtf((float)cnt[t] + 1.0f);
    }
    __syncthreads();
    for (int e = e0 + t; e < e1; e += 256) {
        unsigned p = pairs[e];
        int r = atomicAdd(&cur[p >> 22], 1);
        colidx[r] = (int)(p & 0x3FFFFFu);
    }
}

// ================= network (bf16 hidden states) =================
// K-split z-broadcast: lane j reads only its K-half of z (8 x b128,
// 2 addresses/wave-instr = free 2-way broadcast) and holds weights for
// outputs j and j^32 over that half. One shfl_xor(32) combines halves.
// Halves the per-node LDS-pipe occupancy vs 16-read full broadcast.

// fused input + layer0: hl = bf16( dinv * (relu(x@Win+bin) @ W0) )
__global__ __launch_bounds__(256) void k_gemm0(const float* __restrict__ x,
                                               const float* __restrict__ Win,
                                               const float* __restrict__ bin,
                                               const float* __restrict__ W,
                                               const float* __restrict__ dinv,
                                               unsigned short* __restrict__ hl, int N) {
    __shared__ float zbuf[4][64];
    int wv = threadIdx.x >> 6;
    int j = threadIdx.x & 63;
    int kbase = j & 32;                  // this lane's K-half
    float w1[32], w2[32];
#pragma unroll
    for (int k2 = 0; k2 < 32; k2++) {
        w1[k2] = W[(kbase + k2) * 64 + j];
        w2[k2] = W[(kbase + k2) * 64 + (j ^ 32)];
    }
    float wi[12];
#pragma unroll
    for (int k = 0; k < 12; k++) wi[k] = Win[k * 64 + j];
    float bj = bin[j];
    const float4* zh = (const float4*)&zbuf[wv][kbase];
    int wave = (blockIdx.x * 256 + threadIdx.x) >> 6;
    int nw = (gridDim.x * 256) >> 6;
    int node = wave;
    float xa[12];
    if (node < N) {
        const float* xr = x + (size_t)node * 12;
#pragma unroll
        for (int k = 0; k < 12; k++) xa[k] = xr[k];
    }
    for (; node < N; node += nw) {
        int nxt = node + nw;
        float xb[12];
        const float* xr2 = x + (size_t)(nxt < N ? nxt : node) * 12;
#pragma unroll
        for (int k = 0; k < 12; k++) xb[k] = xr2[k];
        float z = bj;
#pragma unroll
        for (int k = 0; k < 12; k++) z = fmaf(xa[k], wi[k], z);
        zbuf[wv][j] = fmaxf(z, 0.0f);
        asm volatile("s_waitcnt lgkmcnt(0)" ::: "memory");
        float a1 = 0.0f, a2 = 0.0f;
#pragma unroll
        for (int kk = 0; kk < 8; kk++) {
            float4 z4 = zh[kk];
            a1 = fmaf(z4.x, w1[4 * kk + 0], a1);
            a1 = fmaf(z4.y, w1[4 * kk + 1], a1);
            a1 = fmaf(z4.z, w1[4 * kk + 2], a1);
            a1 = fmaf(z4.w, w1[4 * kk + 3], a1);
            a2 = fmaf(z4.x, w2[4 * kk + 0], a2);
            a2 = fmaf(z4.y, w2[4 * kk + 1], a2);
            a2 = fmaf(z4.z, w2[4 * kk + 2], a2);
            a2 = fmaf(z4.w, w2[4 * kk + 3], a2);
        }
        float res = a1 + __shfl_xor(a2, 32);
        hl[(size_t)node * 64 + j] = (unsigned short)rne16(res * dinv[node]);
#pragma unroll
        for (int k = 0; k < 12; k++) xa[k] = xb[k];
    }
}

// fused BN-affine+relu + gemm (layers 1,2), K-split; next-node h2 prefetch.
__global__ __launch_bounds__(256) void k_gemmn(const float* __restrict__ W,
                                               const float* __restrict__ ab,
                                               const float* __restrict__ dinv,
                                               const unsigned* __restrict__ h2,
                                               unsigned short* __restrict__ hl, int N) {
    __shared__ float zbuf[4][64];
    int wv = threadIdx.x >> 6;
    int j = threadIdx.x & 63;
    int kbase = j & 32;
    float w1[32], w2[32];
#pragma unroll
    for (int k2 = 0; k2 < 32; k2++) {
        w1[k2] = W[(kbase + k2) * 64 + j];
        w2[k2] = W[(kbase + k2) * 64 + (j ^ 32)];
    }
    float Aj = ab[j], Bj = ab[64 + j];
    const float4* zh = (const float4*)&zbuf[wv][kbase];
    int wave = (blockIdx.x * 256 + threadIdx.x) >> 6;
    int nw = (gridDim.x * 256) >> 6;
    int node = wave;
    unsigned u = (node < N) ? h2[(size_t)node * 32 + (j >> 1)] : 0u;
    for (; node < N; node += nw) {
        int nxt = node + nw;
        unsigned unext = h2[(size_t)(nxt < N ? nxt : node) * 32 + (j >> 1)];
        float h = (j & 1) ? bhi(u) : blo(u);
        zbuf[wv][j] = fmaxf(fmaf(Aj, h, Bj), 0.0f);
        asm volatile("s_waitcnt lgkmcnt(0)" ::: "memory");
        float a1 = 0.0f, a2 = 0.0f;
#pragma unroll
        for (int kk = 0; kk < 8; kk++) {
            float4 z4 = zh[kk];
            a1 = fmaf(z4.x, w1[4 * kk + 0], a1);
            a1 = fmaf(z4.y, w1[4 * kk + 1], a1);
            a1 = fmaf(z4.z, w1[4 * kk + 2], a1);
            a1 = fmaf(z4.w, w1[4 * kk + 3], a1);
            a2 = fmaf(z4.x, w2[4 * kk + 0], a2);
            a2 = fmaf(z4.y, w2[4 * kk + 1], a2);
            a2 = fmaf(z4.z, w2[4 * kk + 2], a2);
            a2 = fmaf(z4.w, w2[4 * kk + 3], a2);
        }
        float res = a1 + __shfl_xor(a2, 32);
        hl[(size_t)node * 64 + j] = (unsigned short)rne16(res * dinv[node]);
        u = unext;
    }
}

// gather: out[d] = bf16( dinv[d]*(hl[d] + sum_s hl[s]) + b )
// non-persistent, 2-bank accumulators; half-wave per dst; range [d0,dend)
// (split in halves this round so dense kernels surface in rocprof top-5).
__global__ __launch_bounds__(256) void k_agg(const int* __restrict__ rowptr,
                                             const int* __restrict__ rowend,
                                             const int* __restrict__ colidx,
                                             const float* __restrict__ dinv,
                                             const unsigned* __restrict__ hl2,
                                             const float* __restrict__ b,
                                             unsigned* __restrict__ out2,
                                             int d0, int dend) {
    int t = threadIdx.x;
    int hw = t >> 5;            // half-wave id: one dst row each
    int lane = t & 31;
    int sub = lane >> 3;        // edge slot 0..3
    int q = lane & 7;           // uint4 chunk within the 128B row
    int d = d0 + blockIdx.x * 8 + hw;
    if (d >= dend) return;
    int e0 = rowptr[d], e1 = rowend[d];
    const uint4* H = (const uint4*)hl2;   // 8 x uint4 per 64-feat bf16 row

    float a0 = 0.f, a1 = 0.f, a2 = 0.f, a3 = 0.f;
    float a4 = 0.f, a5 = 0.f, a6 = 0.f, a7 = 0.f;
    float c0 = 0.f, c1 = 0.f, c2 = 0.f, c3 = 0.f;
    float c4 = 0.f, c5 = 0.f, c6 = 0.f, c7 = 0.f;

    if (sub == 0) {            // self-loop term, added once
        uint4 su = H[d * 8 + q];
        a0 = blo(su.x); a1 = bhi(su.x);
        a2 = blo(su.y); a3 = bhi(su.y);
        a4 = blo(su.z); a5 = bhi(su.z);
        a6 = blo(su.w); a7 = bhi(su.w);
    }

    int e = e0 + sub;
    for (; e + 12 < e1; e += 16) {
        int s0 = colidx[e];
        int s1 = colidx[e + 4];
        int s2 = colidx[e + 8];
        int s3 = colidx[e + 12];
        uint4 u0 = H[s0 * 8 + q];
        uint4 u1 = H[s1 * 8 + q];
        uint4 u2 = H[s2 * 8 + q];
        uint4 u3 = H[s3 * 8 + q];
        a0 += blo(u0.x); a1 += bhi(u0.x); a2 += blo(u0.y); a3 += bhi(u0.y);
        a4 += blo(u0.z); a5 += bhi(u0.z); a6 += blo(u0.w); a7 += bhi(u0.w);
        c0 += blo(u1.x); c1 += bhi(u1.x); c2 += blo(u1.y); c3 += bhi(u1.y);
        c4 += blo(u1.z); c5 += bhi(u1.z); c6 += blo(u1.w); c7 += bhi(u1.w);
        a0 += blo(u2.x); a1 += bhi(u2.x); a2 += blo(u2.y); a3 += bhi(u2.y);
        a4 += blo(u2.z); a5 += bhi(u2.z); a6 += blo(u2.w); a7 += bhi(u2.w);
        c0 += blo(u3.x); c1 += bhi(u3.x); c2 += blo(u3.y); c3 += bhi(u3.y);
        c4 += blo(u3.z); c5 += bhi(u3.z); c6 += blo(u3.w); c7 += bhi(u3.w);
    }
    for (; e < e1; e += 4) {
        uint4 u = H[colidx[e] * 8 + q];
        a0 += blo(u.x); a1 += bhi(u.x); a2 += blo(u.y); a3 += bhi(u.y);
        a4 += blo(u.z); a5 += bhi(u.z); a6 += blo(u.w); a7 += bhi(u.w);
    }
    a0 += c0; a1 += c1; a2 += c2; a3 += c3;
    a4 += c4; a5 += c5; a6 += c6; a7 += c7;

    // butterfly across the 4 edge slots (stays inside the half-wave)
    a0 += __shfl_xor(a0, 8);  a0 += __shfl_xor(a0, 16);
    a1 += __shfl_xor(a1, 8);  a1 += __shfl_xor(a1, 16);
    a2 += __shfl_xor(a2, 8);  a2 += __shfl_xor(a2, 16);
    a3 += __shfl_xor(a3, 8);  a3 += __shfl_xor(a3, 16);
    a4 += __shfl_xor(a4, 8);  a4 += __shfl_xor(a4, 16);
    a5 += __shfl_xor(a5, 8);  a5 += __shfl_xor(a5, 16);
    a6 += __shfl_xor(a6, 8);  a6 += __shfl_xor(a6, 16);
    a7 += __shfl_xor(a7, 8);  a7 += __shfl_xor(a7, 16);

    if (sub == 0) {
        float dv = dinv[d];
        int fb = q * 8;
        float o0 = fmaf(a0, dv, b[fb + 0]);
        float o1 = fmaf(a1, dv, b[fb + 1]);
        float o2 = fmaf(a2, dv, b[fb + 2]);
        float o3 = fmaf(a3, dv, b[fb + 3]);
        float o4 = fmaf(a4, dv, b[fb + 4]);
        float o5 = fmaf(a5, dv, b[fb + 5]);
        float o6 = fmaf(a6, dv, b[fb + 6]);
        float o7 = fmaf(a7, dv, b[fb + 7]);
        uint4 o;
        o.x = pk(o0, o1);
        o.y = pk(o2, o3);
        o.z = pk(o4, o5);
        o.w = pk(o6, o7);
        ((uint4*)out2)[d * 8 + q] = o;
    }
}

// BN stats + reduce fused: 4-row ILP, block LDS reduce, 128 fire-and-forget
// device atomics into ps[128]; last block (ticket) computes ab[] in-place.
__global__ __launch_bounds__(256) void k_statsred(const unsigned* __restrict__ h2,
                                                  float* __restrict__ ps,
                                                  int* __restrict__ ticket,
                                                  const float* __restrict__ gamma,
                                                  const float* __restrict__ beta,
                                                  float* __restrict__ ab,
                                                  int N, float invN) {
    int t = threadIdx.x;
    int hw = t >> 5, f = t & 31;
    float s0 = 0.f, s1 = 0.f, q0 = 0.f, q1 = 0.f;
    int stride = gridDim.x << 3;          // rows per sweep
    int n = blockIdx.x * 8 + hw;
    for (; n + 3 * stride < N; n += stride << 2) {
        unsigned ua = h2[(size_t)n * 32 + f];
        unsigned ub = h2[((size_t)n + stride) * 32 + f];
        unsigned uc = h2[((size_t)n + 2 * stride) * 32 + f];
        unsigned ud = h2[((size_t)n + 3 * stride) * 32 + f];
        float r;
        r = blo(ua); s0 += r; q0 = fmaf(r, r, q0);
        r = bhi(ua); s1 += r; q1 = fmaf(r, r, q1);
        r = blo(ub); s0 += r; q0 = fmaf(r, r, q0);
        r = bhi(ub); s1 += r; q1 = fmaf(r, r, q1);
        r = blo(uc); s0 += r; q0 = fmaf(r, r, q0);
        r = bhi(uc); s1 += r; q1 = fmaf(r, r, q1);
        r = blo(ud); s0 += r; q0 = fmaf(r, r, q0);
        r = bhi(ud); s1 += r; q1 = fmaf(r, r, q1);
    }
    for (; n < N; n += stride) {
        unsigned u = h2[(size_t)n * 32 + f];
        float r;
        r = blo(u); s0 += r; q0 = fmaf(r, r, q0);
        r = bhi(u); s1 += r; q1 = fmaf(r, r, q1);
    }
    __shared__ float rs[8][64];
    __shared__ float rq[8][64];
    __shared__ int lastflag;
    rs[hw][2 * f] = s0; rs[hw][2 * f + 1] = s1;
    rq[hw][2 * f] = q0; rq[hw][2 * f + 1] = q1;
    __syncthreads();
    if (t < 128) {
        float acc = 0.f;
#pragma unroll
        for (int h = 0; h < 8; h++) acc += (t < 64) ? rs[h][t] : rq[h][t - 64];
        atomicAdd(&ps[t], acc);
    }
    __syncthreads();               // drains the atomics (vmcnt) before ticket
    if (t == 0) {
        __threadfence();
        lastflag = (atomicAdd(ticket, 1) == (int)gridDim.x - 1);
    }
    __syncthreads();
    if (lastflag && t < 64) {
        float S = atomicAdd(&ps[t], 0.0f);        // device-coherent read
        float Q = atomicAdd(&ps[64 + t], 0.0f);
        float mu = S * invN;
        float var = fmaf(-mu, mu, Q * invN);
        float A = rsqrtf(var + EPSV) * gamma[t];
        ab[t] = A;
        ab[64 + t] = fmaf(-mu, A, beta[t]);
    }
}

// classifier with BN2 affine folded into W1/b1 (no relu after BN2)
__global__ __launch_bounds__(256, 2) void k_cls(const unsigned* __restrict__ h2,
                                                const float* __restrict__ ab,
                                                const float* __restrict__ W1,
                                                const float* __restrict__ b1,
                                                const float* __restrict__ W2,
                                                const float* __restrict__ b2,
                                                float* __restrict__ out, int N) {
    int lane = threadIdx.x & 63;
    int half = lane >> 5, jj = lane & 31;
    float w[64];
    float bj = b1[jj];
#pragma unroll
    for (int k = 0; k < 64; k++) {
        float w1 = W1[k * 32 + jj];
        w[k] = ab[k] * w1;
        bj = fmaf(ab[64 + k], w1, bj);
    }
    float w20 = W2[jj * 2 + 0], w21 = W2[jj * 2 + 1];
    float b20 = b2[0], b21 = b2[1];
    int wave = (blockIdx.x * 256 + threadIdx.x) >> 6;
    int nw = (gridDim.x * 256) >> 6;
    for (int base = wave * 2; base < N; base += nw * 2) {
        int node = base + half;
        int vnode = node < N ? node : 0;
        const uint4* row = (const uint4*)(h2 + vnode * 32);
        float A0 = bj, A1 = 0.f, A2 = 0.f, A3 = 0.f;
#pragma unroll
        for (int kk = 0; kk < 8; kk++) {
            uint4 u = row[kk];
            A0 = fmaf(blo(u.x), w[8 * kk + 0], A0);
            A1 = fmaf(bhi(u.x), w[8 * kk + 1], A1);
            A2 = fmaf(blo(u.y), w[8 * kk + 2], A2);
            A3 = fmaf(bhi(u.y), w[8 * kk + 3], A3);
            A0 = fmaf(blo(u.z), w[8 * kk + 4], A0);
            A1 = fmaf(bhi(u.z), w[8 * kk + 5], A1);
            A2 = fmaf(blo(u.w), w[8 * kk + 6], A2);
            A3 = fmaf(bhi(u.w), w[8 * kk + 7], A3);
        }
        float acc = (A0 + A1) + (A2 + A3);
        float hv = fmaxf(acc, 0.0f);
        float t0 = hv * w20, t1 = hv * w21;
#pragma unroll
        for (int m = 1; m <= 16; m <<= 1) {
            t0 += __shfl_xor(t0, m, 64);
            t1 += __shfl_xor(t1, m, 64);
        }
        if (jj == 0 && node < N) {
            ((float2*)out)[node] = make_float2(t0 + b20, t1 + b21);
        }
    }
}

extern "C" void kernel_launch(void* const* d_in, const int* in_sizes, int n_in,
                              void* d_out, int out_size, void* d_ws, size_t ws_size,
                              hipStream_t stream) {
    const float* x     = (const float*)d_in[0];
    const int*   ei    = (const int*)d_in[1];
    const float* Win   = (const float*)d_in[2];
    const float* bin   = (const float*)d_in[3];
    const float* Wg    = (const float*)d_in[4];
    const float* bg    = (const float*)d_in[5];
    const float* gamma = (const float*)d_in[6];
    const float* beta  = (const float*)d_in[7];
    const float* W1    = (const float*)d_in[8];
    const float* b1    = (const float*)d_in[9];
    const float* W2    = (const float*)d_in[10];
    const float* b2    = (const float*)d_in[11];
    float* out = (float*)d_out;

    int N = in_sizes[0] / 12;
    int E = in_sizes[1] / 2;
    const int* src = ei;
    const int* dst = ei + E;
    float invN = 1.0f / (float)N;
    int NB = (N + BSZ - 1) >> BSH;
    int NBLK = (E + 4095) / 4096;        // build blocks

    char* ws = (char*)d_ws;
    size_t szhin = ((size_t)N * 64 * 2 + 255) / 256 * 256;  // bf16 hidden
    size_t szE4  = ((size_t)E * 4 + 255) / 256 * 256;
    size_t szN4  = ((size_t)N * 4 + 255) / 256 * 256;

    size_t off = 0;
    unsigned* hin2     = (unsigned*)(ws + off); off += szhin;
    unsigned short* hl = (unsigned short*)(ws + off); off += szhin;
    int* colidx        = (int*)(ws + off); off += szE4;
    int* rowptr        = (int*)(ws + off); off += szN4;
    int* rowend        = (int*)(ws + off); off += szN4;
    float* dinv        = (float*)(ws + off); off += szN4;
    int* bcount        = (int*)(ws + off); off += 4096;
    float* ps3         = (float*)(ws + off); off += 3 * 512;  // 3x128 floats
    int* tick          = (int*)(ws + off); off += 32;         // 4+ tickets
    int* bstart        = (int*)(ws + off); off += 8192;       // 1025 ints
    float* ab          = (float*)(ws + off); off += 512;

    // pairs (E*4) aliases hin2 region; histmat (NBLK*4KB) aliases hl region.
    // Both are dead before k_gemm0 first writes hl.
    unsigned* pairs = (unsigned*)ws;
    int* histmat = (int*)(ws + szhin);
    size_t need = off;
    if ((size_t)E * 4 > szhin || (size_t)NBLK * 4096 > szhin) {
        pairs = (unsigned*)(ws + off);
        histmat = (int*)(ws + off + szE4);
        need = off + szE4 + (size_t)NBLK * 4096;
    }
    if (ws_size < need || NB > 1024 || N >= (1 << 22) || NBLK > 3072)
        return;  // loud failure

    k_hist<<<NBLK, 256, 0, stream>>>(dst, histmat, tick + 3, E);
    k_scanb<<<256, 256, 0, stream>>>(histmat, bcount, bstart, tick + 3,
                                     ps3, tick, NBLK);
    k_split<<<NBLK, 256, 0, stream>>>(src, dst, histmat, bstart, pairs, E);
    k_build<<<NB, 256, 0, stream>>>(pairs, bstart, rowptr, rowend, dinv, colidx, N);

    int NH = (N + 1) / 2;                 // first-half rows (diagnostic split)
    int AB1 = (NH + 7) / 8;
    int AB2 = (N - NH + 7) / 8;
    for (int i = 0; i < 3; i++) {
        if (i == 0)
            k_gemm0<<<2048, 256, 0, stream>>>(x, Win, bin, Wg, dinv, hl, N);
        else
            k_gemmn<<<2048, 256, 0, stream>>>(Wg + i * 64 * 64, ab, dinv, hin2,
                                              hl, N);
        k_agg<<<AB1, 256, 0, stream>>>(rowptr, rowend, colidx, dinv,
                                       (const unsigned*)hl, bg + i * 64, hin2,
                                       0, NH);
        k_agg<<<AB2, 256, 0, stream>>>(rowptr, rowend, colidx, dinv,
                                       (const unsigned*)hl, bg + i * 64, hin2,
                                       NH, N);
        k_statsred<<<SBR, 256, 0, stream>>>(hin2, ps3 + i * 128, tick + i,
                                            gamma + i * 64, beta + i * 64, ab,
                                            N, invN);
    }
    k_cls<<<1024, 256, 0, stream>>>(hin2, ab, W1, b1, W2, b2, out, N);
}

// Round 17
// 459.679 us; speedup vs baseline: 1.0402x; 1.0402x over previous
//
#include <hip/hip_runtime.h>

#define EPSV 1e-5f
#define BSH 8           // bucket shift: 256 nodes per bucket
#define BSZ 256
#define SBR 416         // statsred blocks

// bf16x2 helpers (bf16 = top 16 bits of fp32; element 2f = low half)
__device__ inline float blo(unsigned u) { return __uint_as_float(u << 16); }
__device__ inline float bhi(unsigned u) { return __uint_as_float(u & 0xFFFF0000u); }
__device__ inline unsigned rne16(float v) {
    unsigned u = __float_as_uint(v);
    return (u + 0x7FFFu + ((u >> 16) & 1u)) >> 16;
}
__device__ inline unsigned pk(float lo, float hi) {
    return (rne16(hi) << 16) | rne16(lo);
}

// ====== CSR build: deterministic multisplit (histmat, no global atomics) ===

// per-block LDS hist -> coalesced 4KB row store to histmat[block][1024].
// Block 0 also zeroes k_scanb's ticket (replaces the memset dispatch).
__global__ __launch_bounds__(256) void k_hist(const int* __restrict__ dst,
                                              int* __restrict__ histmat,
                                              int* __restrict__ tick3, int E) {
    __shared__ int hist[1024];
    int t = threadIdx.x;
    if (blockIdx.x == 0 && t == 0) tick3[0] = 0;
#pragma unroll
    for (int i = 0; i < 4; i++) hist[t + 256 * i] = 0;
    __syncthreads();
    int e0 = blockIdx.x * 4096;
#pragma unroll
    for (int r = 0; r < 16; r++) {
        int e = e0 + r * 256 + t;
        if (e < E) atomicAdd(&hist[dst[e] >> BSH], 1);
    }
    __syncthreads();
    int* hrow = histmat + (size_t)blockIdx.x * 1024;
#pragma unroll
    for (int i = 0; i < 4; i++) hrow[t + 256 * i] = hist[t + 256 * i];
}

// one wave per bucket: exclusive scan of histmat column (over blocks),
// in-place; bucket total -> bcount. Last block (ticket) scans bcount->bstart
// and zeroes the statsred partials/tickets for this launch.
__global__ __launch_bounds__(256) void k_scanb(int* __restrict__ histmat,
                                               int* __restrict__ bcount,
                                               int* __restrict__ bstart,
                                               int* __restrict__ ticket,
                                               float* __restrict__ ps3,
                                               int* __restrict__ tick012,
                                               int NBLK) {
    int t = threadIdx.x;
    int wv = t >> 6, lane = t & 63;
    int bucket = blockIdx.x * 4 + wv;     // grid 256 -> 1024 buckets
    int run = 0;
    int lim = (NBLK + 63) & ~63;
    for (int i = lane; i < lim; i += 64) {
        int v = (i < NBLK) ? histmat[(size_t)i * 1024 + bucket] : 0;
        int s = v;
#pragma unroll
        for (int d = 1; d < 64; d <<= 1) {
            int up = __shfl_up(s, d, 64);
            if (lane >= d) s += up;
        }
        if (i < NBLK) histmat[(size_t)i * 1024 + bucket] = run + s - v;
        run += __shfl(s, 63, 64);
    }
    if (lane == 0) bcount[bucket] = run;
    __syncthreads();
    __shared__ int lastflag;
    if (t == 0) {
        __threadfence();
        lastflag = (atomicAdd(ticket, 1) == (int)gridDim.x - 1);
    }
    __syncthreads();
    if (lastflag) {
        for (int i = t; i < 384; i += 256) ps3[i] = 0.0f;
        if (t < 3) tick012[t] = 0;
        int base = t * 4;
        int c[4], s2 = 0;
#pragma unroll
        for (int i = 0; i < 4; i++) {
            c[i] = atomicAdd(&bcount[base + i], 0);   // device-coherent read
            s2 += c[i];
        }
        __shared__ int ls[256];
        ls[t] = s2;
        __syncthreads();
        for (int off = 1; off < 256; off <<= 1) {
            int x = (t >= off) ? ls[t - off] : 0;
            __syncthreads();
            ls[t] += x;
            __syncthreads();
        }
        int run2 = (t == 0) ? 0 : ls[t - 1];
#pragma unroll
        for (int i = 0; i < 4; i++) {
            bstart[base + i] = run2;
            run2 += c[i];
        }
        if (t == 255) bstart[1024] = ls[255];
    }
}

// single-pass split: offsets precomputed (bstart + histmat excl), rank via
// LDS atomic. pack: (dst_local << 22) | src   (src < 2^22, dst_local < 256)
__global__ __launch_bounds__(256) void k_split(const int* __restrict__ src,
                                               const int* __restrict__ dst,
                                               const int* __restrict__ histmat,
                                               const int* __restrict__ bstart,
                                               unsigned* __restrict__ pairs, int E) {
    __shared__ int hist[1024];
    __shared__ int gb[1024];
    int t = threadIdx.x;
    int e0 = blockIdx.x * 4096;
    const int* hrow = histmat + (size_t)blockIdx.x * 1024;
    int sreg[16], dreg[16];
#pragma unroll
    for (int i = 0; i < 4; i++) {
        int bk = t + 256 * i;
        hist[bk] = 0;
        gb[bk] = bstart[bk] + hrow[bk];
    }
#pragma unroll
    for (int r = 0; r < 16; r++) {
        int e = e0 + r * 256 + t;
        if (e < E) {
            sreg[r] = src[e];
            dreg[r] = dst[e];
        } else {
            dreg[r] = -1;
        }
    }
    __syncthreads();
#pragma unroll
    for (int r = 0; r < 16; r++) {
        if (dreg[r] >= 0) {
            int bk = dreg[r] >> BSH;
            int rk = atomicAdd(&hist[bk], 1);
            pairs[gb[bk] + rk] = ((unsigned)(dreg[r] & (BSZ - 1)) << 22) |
                                 (unsigned)sreg[r];
        }
    }
}

// one block per 256-node bucket
__global__ __launch_bounds__(256) void k_build(const unsigned* __restrict__ pairs,
                                               const int* __restrict__ bstart,
                                               int* __restrict__ rowptr,
                                               int* __restrict__ rowend,
                                               float* __restrict__ dinv,
                                               int* __restrict__ colidx, int N) {
    int bid = blockIdx.x, t = threadIdx.x;
    int n0 = bid << BSH;
    int e0 = bstart[bid], e1 = bstart[bid + 1];
    __shared__ int cnt[256];
    __shared__ int ls[256];
    __shared__ int cur[256];
    cnt[t] = 0;
    __syncthreads();
    for (int e = e0 + t; e < e1; e += 256)
        atomicAdd(&cnt[pairs[e] >> 22], 1);
    __syncthreads();
    ls[t] = cnt[t];
    __syncthreads();
    for (int off = 1; off < 256; off <<= 1) {
        int x = (t >= off) ? ls[t - off] : 0;
        __syncthreads();
        ls[t] += x;
        __syncthreads();
    }
    int start = e0 + ((t == 0) ? 0 : ls[t - 1]);
    cur[t] = start;
    int node = n0 + t;
    if (node < N) {
        rowptr[node] = start;
        rowend[node] = start + cnt[t];
        dinv[node] = rsqrtf((float)cnt[t] + 1.0f);
    }
    __syncthreads();
    for (int e = e0 + t; e < e1; e += 256) {
        unsigned p = pairs[e];
        int r = atomicAdd(&cur[p >> 22], 1);
        colidx[r] = (int)(p & 0x3FFFFFu);
    }
}

// ================= network (bf16 hidden states) =================
// K-split z-broadcast: lane j reads only its K-half of z (8 x b128,
// 2 addresses/wave-instr = free 2-way broadcast) and holds weights for
// outputs j and j^32 over that half. One shfl_xor(32) combines halves.

// fused input + layer0: hl = bf16( dinv * (relu(x@Win+bin) @ W0) )
__global__ __launch_bounds__(256) void k_gemm0(const float* __restrict__ x,
                                               const float* __restrict__ Win,
                                               const float* __restrict__ bin,
                                               const float* __restrict__ W,
                                               const float* __restrict__ dinv,
                                               unsigned short* __restrict__ hl, int N) {
    __shared__ float zbuf[4][64];
    int wv = threadIdx.x >> 6;
    int j = threadIdx.x & 63;
    int kbase = j & 32;                  // this lane's K-half
    float w1[32], w2[32];
#pragma unroll
    for (int k2 = 0; k2 < 32; k2++) {
        w1[k2] = W[(kbase + k2) * 64 + j];
        w2[k2] = W[(kbase + k2) * 64 + (j ^ 32)];
    }
    float wi[12];
#pragma unroll
    for (int k = 0; k < 12; k++) wi[k] = Win[k * 64 + j];
    float bj = bin[j];
    const float4* zh = (const float4*)&zbuf[wv][kbase];
    int wave = (blockIdx.x * 256 + threadIdx.x) >> 6;
    int nw = (gridDim.x * 256) >> 6;
    int node = wave;
    float xa[12];
    if (node < N) {
        const float* xr = x + (size_t)node * 12;
#pragma unroll
        for (int k = 0; k < 12; k++) xa[k] = xr[k];
    }
    for (; node < N; node += nw) {
        int nxt = node + nw;
        float xb[12];
        const float* xr2 = x + (size_t)(nxt < N ? nxt : node) * 12;
#pragma unroll
        for (int k = 0; k < 12; k++) xb[k] = xr2[k];
        float z = bj;
#pragma unroll
        for (int k = 0; k < 12; k++) z = fmaf(xa[k], wi[k], z);
        zbuf[wv][j] = fmaxf(z, 0.0f);
        asm volatile("s_waitcnt lgkmcnt(0)" ::: "memory");
        float a1 = 0.0f, a2 = 0.0f;
#pragma unroll
        for (int kk = 0; kk < 8; kk++) {
            float4 z4 = zh[kk];
            a1 = fmaf(z4.x, w1[4 * kk + 0], a1);
            a1 = fmaf(z4.y, w1[4 * kk + 1], a1);
            a1 = fmaf(z4.z, w1[4 * kk + 2], a1);
            a1 = fmaf(z4.w, w1[4 * kk + 3], a1);
            a2 = fmaf(z4.x, w2[4 * kk + 0], a2);
            a2 = fmaf(z4.y, w2[4 * kk + 1], a2);
            a2 = fmaf(z4.z, w2[4 * kk + 2], a2);
            a2 = fmaf(z4.w, w2[4 * kk + 3], a2);
        }
        float res = a1 + __shfl_xor(a2, 32);
        hl[(size_t)node * 64 + j] = (unsigned short)rne16(res * dinv[node]);
#pragma unroll
        for (int k = 0; k < 12; k++) xa[k] = xb[k];
    }
}

// fused BN-affine+relu + gemm (layers 1,2), K-split; next-node h2 prefetch.
__global__ __launch_bounds__(256) void k_gemmn(const float* __restrict__ W,
                                               const float* __restrict__ ab,
                                               const float* __restrict__ dinv,
                                               const unsigned* __restrict__ h2,
                                               unsigned short* __restrict__ hl, int N) {
    __shared__ float zbuf[4][64];
    int wv = threadIdx.x >> 6;
    int j = threadIdx.x & 63;
    int kbase = j & 32;
    float w1[32], w2[32];
#pragma unroll
    for (int k2 = 0; k2 < 32; k2++) {
        w1[k2] = W[(kbase + k2) * 64 + j];
        w2[k2] = W[(kbase + k2) * 64 + (j ^ 32)];
    }
    float Aj = ab[j], Bj = ab[64 + j];
    const float4* zh = (const float4*)&zbuf[wv][kbase];
    int wave = (blockIdx.x * 256 + threadIdx.x) >> 6;
    int nw = (gridDim.x * 256) >> 6;
    int node = wave;
    unsigned u = (node < N) ? h2[(size_t)node * 32 + (j >> 1)] : 0u;
    for (; node < N; node += nw) {
        int nxt = node + nw;
        unsigned unext = h2[(size_t)(nxt < N ? nxt : node) * 32 + (j >> 1)];
        float h = (j & 1) ? bhi(u) : blo(u);
        zbuf[wv][j] = fmaxf(fmaf(Aj, h, Bj), 0.0f);
        asm volatile("s_waitcnt lgkmcnt(0)" ::: "memory");
        float a1 = 0.0f, a2 = 0.0f;
#pragma unroll
        for (int kk = 0; kk < 8; kk++) {
            float4 z4 = zh[kk];
            a1 = fmaf(z4.x, w1[4 * kk + 0], a1);
            a1 = fmaf(z4.y, w1[4 * kk + 1], a1);
            a1 = fmaf(z4.z, w1[4 * kk + 2], a1);
            a1 = fmaf(z4.w, w1[4 * kk + 3], a1);
            a2 = fmaf(z4.x, w2[4 * kk + 0], a2);
            a2 = fmaf(z4.y, w2[4 * kk + 1], a2);
            a2 = fmaf(z4.z, w2[4 * kk + 2], a2);
            a2 = fmaf(z4.w, w2[4 * kk + 3], a2);
        }
        float res = a1 + __shfl_xor(a2, 32);
        hl[(size_t)node * 64 + j] = (unsigned short)rne16(res * dinv[node]);
        u = unext;
    }
}

// gather: out[d] = bf16( dinv[d]*(hl[d] + sum_s hl[s]) + b )
// non-persistent, 2-bank accumulators (measured 53.0us, VGPR 28, occ 70%):
// half-wave per dst; 4 edge slots x 8 lanes x uint4; 16 edges in flight.
__global__ __launch_bounds__(256) void k_agg(const int* __restrict__ rowptr,
                                             const int* __restrict__ rowend,
                                             const int* __restrict__ colidx,
                                             const float* __restrict__ dinv,
                                             const unsigned* __restrict__ hl2,
                                             const float* __restrict__ b,
                                             unsigned* __restrict__ out2, int N) {
    int t = threadIdx.x;
    int hw = t >> 5;            // half-wave id: one dst row each
    int lane = t & 31;
    int sub = lane >> 3;        // edge slot 0..3
    int q = lane & 7;           // uint4 chunk within the 128B row
    int d = blockIdx.x * 8 + hw;
    if (d >= N) return;
    int e0 = rowptr[d], e1 = rowend[d];
    const uint4* H = (const uint4*)hl2;   // 8 x uint4 per 64-feat bf16 row

    float a0 = 0.f, a1 = 0.f, a2 = 0.f, a3 = 0.f;
    float a4 = 0.f, a5 = 0.f, a6 = 0.f, a7 = 0.f;
    float c0 = 0.f, c1 = 0.f, c2 = 0.f, c3 = 0.f;
    float c4 = 0.f, c5 = 0.f, c6 = 0.f, c7 = 0.f;

    if (sub == 0) {            // self-loop term, added once
        uint4 su = H[d * 8 + q];
        a0 = blo(su.x); a1 = bhi(su.x);
        a2 = blo(su.y); a3 = bhi(su.y);
        a4 = blo(su.z); a5 = bhi(su.z);
        a6 = blo(su.w); a7 = bhi(su.w);
    }

    int e = e0 + sub;
    for (; e + 12 < e1; e += 16) {
        int s0 = colidx[e];
        int s1 = colidx[e + 4];
        int s2 = colidx[e + 8];
        int s3 = colidx[e + 12];
        uint4 u0 = H[s0 * 8 + q];
        uint4 u1 = H[s1 * 8 + q];
        uint4 u2 = H[s2 * 8 + q];
        uint4 u3 = H[s3 * 8 + q];
        a0 += blo(u0.x); a1 += bhi(u0.x); a2 += blo(u0.y); a3 += bhi(u0.y);
        a4 += blo(u0.z); a5 += bhi(u0.z); a6 += blo(u0.w); a7 += bhi(u0.w);
        c0 += blo(u1.x); c1 += bhi(u1.x); c2 += blo(u1.y); c3 += bhi(u1.y);
        c4 += blo(u1.z); c5 += bhi(u1.z); c6 += blo(u1.w); c7 += bhi(u1.w);
        a0 += blo(u2.x); a1 += bhi(u2.x); a2 += blo(u2.y); a3 += bhi(u2.y);
        a4 += blo(u2.z); a5 += bhi(u2.z); a6 += blo(u2.w); a7 += bhi(u2.w);
        c0 += blo(u3.x); c1 += bhi(u3.x); c2 += blo(u3.y); c3 += bhi(u3.y);
        c4 += blo(u3.z); c5 += bhi(u3.z); c6 += blo(u3.w); c7 += bhi(u3.w);
    }
    for (; e < e1; e += 4) {
        uint4 u = H[colidx[e] * 8 + q];
        a0 += blo(u.x); a1 += bhi(u.x); a2 += blo(u.y); a3 += bhi(u.y);
        a4 += blo(u.z); a5 += bhi(u.z); a6 += blo(u.w); a7 += bhi(u.w);
    }
    a0 += c0; a1 += c1; a2 += c2; a3 += c3;
    a4 += c4; a5 += c5; a6 += c6; a7 += c7;

    // butterfly across the 4 edge slots (stays inside the half-wave)
    a0 += __shfl_xor(a0, 8);  a0 += __shfl_xor(a0, 16);
    a1 += __shfl_xor(a1, 8);  a1 += __shfl_xor(a1, 16);
    a2 += __shfl_xor(a2, 8);  a2 += __shfl_xor(a2, 16);
    a3 += __shfl_xor(a3, 8);  a3 += __shfl_xor(a3, 16);
    a4 += __shfl_xor(a4, 8);  a4 += __shfl_xor(a4, 16);
    a5 += __shfl_xor(a5, 8);  a5 += __shfl_xor(a5, 16);
    a6 += __shfl_xor(a6, 8);  a6 += __shfl_xor(a6, 16);
    a7 += __shfl_xor(a7, 8);  a7 += __shfl_xor(a7, 16);

    if (sub == 0) {
        float dv = dinv[d];
        int fb = q * 8;
        float o0 = fmaf(a0, dv, b[fb + 0]);
        float o1 = fmaf(a1, dv, b[fb + 1]);
        float o2 = fmaf(a2, dv, b[fb + 2]);
        float o3 = fmaf(a3, dv, b[fb + 3]);
        float o4 = fmaf(a4, dv, b[fb + 4]);
        float o5 = fmaf(a5, dv, b[fb + 5]);
        float o6 = fmaf(a6, dv, b[fb + 6]);
        float o7 = fmaf(a7, dv, b[fb + 7]);
        uint4 o;
        o.x = pk(o0, o1);
        o.y = pk(o2, o3);
        o.z = pk(o4, o5);
        o.w = pk(o6, o7);
        ((uint4*)out2)[d * 8 + q] = o;
    }
}

// BN stats + reduce fused: 4-row ILP, block LDS reduce, 128 fire-and-forget
// device atomics into ps[128]; last block (ticket) computes ab[] in-place.
__global__ __launch_bounds__(256) void k_statsred(const unsigned* __restrict__ h2,
                                                  float* __restrict__ ps,
                                                  int* __restrict__ ticket,
                                                  const float* __restrict__ gamma,
                                                  const float* __restrict__ beta,
                                                  float* __restrict__ ab,
                                                  int N, float invN) {
    int t = threadIdx.x;
    int hw = t >> 5, f = t & 31;
    float s0 = 0.f, s1 = 0.f, q0 = 0.f, q1 = 0.f;
    int stride = gridDim.x << 3;          // rows per sweep
    int n = blockIdx.x * 8 + hw;
    for (; n + 3 * stride < N; n += stride << 2) {
        unsigned ua = h2[(size_t)n * 32 + f];
        unsigned ub = h2[((size_t)n + stride) * 32 + f];
        unsigned uc = h2[((size_t)n + 2 * stride) * 32 + f];
        unsigned ud = h2[((size_t)n + 3 * stride) * 32 + f];
        float r;
        r = blo(ua); s0 += r; q0 = fmaf(r, r, q0);
        r = bhi(ua); s1 += r; q1 = fmaf(r, r, q1);
        r = blo(ub); s0 += r; q0 = fmaf(r, r, q0);
        r = bhi(ub); s1 += r; q1 = fmaf(r, r, q1);
        r = blo(uc); s0 += r; q0 = fmaf(r, r, q0);
        r = bhi(uc); s1 += r; q1 = fmaf(r, r, q1);
        r = blo(ud); s0 += r; q0 = fmaf(r, r, q0);
        r = bhi(ud); s1 += r; q1 = fmaf(r, r, q1);
    }
    for (; n < N; n += stride) {
        unsigned u = h2[(size_t)n * 32 + f];
        float r;
        r = blo(u); s0 += r; q0 = fmaf(r, r, q0);
        r = bhi(u); s1 += r; q1 = fmaf(r, r, q1);
    }
    __shared__ float rs[8][64];
    __shared__ float rq[8][64];
    __shared__ int lastflag;
    rs[hw][2 * f] = s0; rs[hw][2 * f + 1] = s1;
    rq[hw][2 * f] = q0; rq[hw][2 * f + 1] = q1;
    __syncthreads();
    if (t < 128) {
        float acc = 0.f;
#pragma unroll
        for (int h = 0; h < 8; h++) acc += (t < 64) ? rs[h][t] : rq[h][t - 64];
        atomicAdd(&ps[t], acc);
    }
    __syncthreads();               // drains the atomics (vmcnt) before ticket
    if (t == 0) {
        __threadfence();
        lastflag = (atomicAdd(ticket, 1) == (int)gridDim.x - 1);
    }
    __syncthreads();
    if (lastflag && t < 64) {
        float S = atomicAdd(&ps[t], 0.0f);        // device-coherent read
        float Q = atomicAdd(&ps[64 + t], 0.0f);
        float mu = S * invN;
        float var = fmaf(-mu, mu, Q * invN);
        float A = rsqrtf(var + EPSV) * gamma[t];
        ab[t] = A;
        ab[64 + t] = fmaf(-mu, A, beta[t]);
    }
}

// classifier with BN2 affine folded into W1/b1 (no relu after BN2)
__global__ __launch_bounds__(256, 2) void k_cls(const unsigned* __restrict__ h2,
                                                const float* __restrict__ ab,
                                                const float* __restrict__ W1,
                                                const float* __restrict__ b1,
                                                const float* __restrict__ W2,
                                                const float* __restrict__ b2,
                                                float* __restrict__ out, int N) {
    int lane = threadIdx.x & 63;
    int half = lane >> 5, jj = lane & 31;
    float w[64];
    float bj = b1[jj];
#pragma unroll
    for (int k = 0; k < 64; k++) {
        float w1 = W1[k * 32 + jj];
        w[k] = ab[k] * w1;
        bj = fmaf(ab[64 + k], w1, bj);
    }
    float w20 = W2[jj * 2 + 0], w21 = W2[jj * 2 + 1];
    float b20 = b2[0], b21 = b2[1];
    int wave = (blockIdx.x * 256 + threadIdx.x) >> 6;
    int nw = (gridDim.x * 256) >> 6;
    for (int base = wave * 2; base < N; base += nw * 2) {
        int node = base + half;
        int vnode = node < N ? node : 0;
        const uint4* row = (const uint4*)(h2 + vnode * 32);
        float A0 = bj, A1 = 0.f, A2 = 0.f, A3 = 0.f;
#pragma unroll
        for (int kk = 0; kk < 8; kk++) {
            uint4 u = row[kk];
            A0 = fmaf(blo(u.x), w[8 * kk + 0], A0);
            A1 = fmaf(bhi(u.x), w[8 * kk + 1], A1);
            A2 = fmaf(blo(u.y), w[8 * kk + 2], A2);
            A3 = fmaf(bhi(u.y), w[8 * kk + 3], A3);
            A0 = fmaf(blo(u.z), w[8 * kk + 4], A0);
            A1 = fmaf(bhi(u.z), w[8 * kk + 5], A1);
            A2 = fmaf(blo(u.w), w[8 * kk + 6], A2);
            A3 = fmaf(bhi(u.w), w[8 * kk + 7], A3);
        }
        float acc = (A0 + A1) + (A2 + A3);
        float hv = fmaxf(acc, 0.0f);
        float t0 = hv * w20, t1 = hv * w21;
#pragma unroll
        for (int m = 1; m <= 16; m <<= 1) {
            t0 += __shfl_xor(t0, m, 64);
            t1 += __shfl_xor(t1, m, 64);
        }
        if (jj == 0 && node < N) {
            ((float2*)out)[node] = make_float2(t0 + b20, t1 + b21);
        }
    }
}

extern "C" void kernel_launch(void* const* d_in, const int* in_sizes, int n_in,
                              void* d_out, int out_size, void* d_ws, size_t ws_size,
                              hipStream_t stream) {
    const float* x     = (const float*)d_in[0];
    const int*   ei    = (const int*)d_in[1];
    const float* Win   = (const float*)d_in[2];
    const float* bin   = (const float*)d_in[3];
    const float* Wg    = (const float*)d_in[4];
    const float* bg    = (const float*)d_in[5];
    const float* gamma = (const float*)d_in[6];
    const float* beta  = (const float*)d_in[7];
    const float* W1    = (const float*)d_in[8];
    const float* b1    = (const float*)d_in[9];
    const float* W2    = (const float*)d_in[10];
    const float* b2    = (const float*)d_in[11];
    float* out = (float*)d_out;

    int N = in_sizes[0] / 12;
    int E = in_sizes[1] / 2;
    const int* src = ei;
    const int* dst = ei + E;
    float invN = 1.0f / (float)N;
    int NB = (N + BSZ - 1) >> BSH;
    int NBLK = (E + 4095) / 4096;        // build blocks

    char* ws = (char*)d_ws;
    size_t szhin = ((size_t)N * 64 * 2 + 255) / 256 * 256;  // bf16 hidden
    size_t szE4  = ((size_t)E * 4 + 255) / 256 * 256;
    size_t szN4  = ((size_t)N * 4 + 255) / 256 * 256;

    size_t off = 0;
    unsigned* hin2     = (unsigned*)(ws + off); off += szhin;
    unsigned short* hl = (unsigned short*)(ws + off); off += szhin;
    int* colidx        = (int*)(ws + off); off += szE4;
    int* rowptr        = (int*)(ws + off); off += szN4;
    int* rowend        = (int*)(ws + off); off += szN4;
    float* dinv        = (float*)(ws + off); off += szN4;
    int* bcount        = (int*)(ws + off); off += 4096;
    float* ps3         = (float*)(ws + off); off += 3 * 512;  // 3x128 floats
    int* tick          = (int*)(ws + off); off += 32;         // 4+ tickets
    int* bstart        = (int*)(ws + off); off += 8192;       // 1025 ints
    float* ab          = (float*)(ws + off); off += 512;

    // pairs (E*4) aliases hin2 region; histmat (NBLK*4KB) aliases hl region.
    // Both are dead before k_gemm0 first writes hl.
    unsigned* pairs = (unsigned*)ws;
    int* histmat = (int*)(ws + szhin);
    size_t need = off;
    if ((size_t)E * 4 > szhin || (size_t)NBLK * 4096 > szhin) {
        pairs = (unsigned*)(ws + off);
        histmat = (int*)(ws + off + szE4);
        need = off + szE4 + (size_t)NBLK * 4096;
    }
    if (ws_size < need || NB > 1024 || N >= (1 << 22) || NBLK > 3072)
        return;  // loud failure

    k_hist<<<NBLK, 256, 0, stream>>>(dst, histmat, tick + 3, E);
    k_scanb<<<256, 256, 0, stream>>>(histmat, bcount, bstart, tick + 3,
                                     ps3, tick, NBLK);
    k_split<<<NBLK, 256, 0, stream>>>(src, dst, histmat, bstart, pairs, E);
    k_build<<<NB, 256, 0, stream>>>(pairs, bstart, rowptr, rowend, dinv, colidx, N);

    int AB = (N + 7) / 8;
    for (int i = 0; i < 3; i++) {
        if (i == 0)
            k_gemm0<<<2048, 256, 0, stream>>>(x, Win, bin, Wg, dinv, hl, N);
        else
            k_gemmn<<<2048, 256, 0, stream>>>(Wg + i * 64 * 64, ab, dinv, hin2,
                                              hl, N);
        k_agg<<<AB, 256, 0, stream>>>(rowptr, rowend, colidx, dinv,
                                      (const unsigned*)hl, bg + i * 64, hin2, N);
        k_statsred<<<SBR, 256, 0, stream>>>(hin2, ps3 + i * 128, tick + i,
                                            gamma + i * 64, beta + i * 64, ab,
                                            N, invN);
    }
    k_cls<<<1024, 256, 0, stream>>>(hin2, ab, W1, b1, W2, b2, out, N);
}